// Round 18
// baseline (814.015 us; speedup 1.0000x reference)
//
#include <hip/hip_runtime.h>
#include <hip/hip_bf16.h>
#include <cstdint>
#include <cstddef>

#define CDIM 128
#define NCELLS 100000
#define SCHUNK 1024

typedef __attribute__((ext_vector_type(8))) short short8;
typedef __attribute__((ext_vector_type(4))) float f32x4;

__device__ __forceinline__ unsigned short f2bf(float f) {
    unsigned u = __float_as_uint(f);
    unsigned r = u + 0x7FFFu + ((u >> 16) & 1u);
    return (unsigned short)(r >> 16);
}
__device__ __forceinline__ float bf2f(unsigned short u) {
    return __uint_as_float(((unsigned)u) << 16);
}
__device__ __forceinline__ float lo16(unsigned u) { return __uint_as_float(u << 16); }
__device__ __forceinline__ float hi16(unsigned u) { return __uint_as_float(u & 0xffff0000u); }
// packed f32x2 -> bf16x2 (1 instr, RNE)
__device__ __forceinline__ unsigned pkbf(float lo, float hi) {
    unsigned r;
    asm("v_cvt_pk_bf16_f32 %0, %1, %2" : "=v"(r) : "v"(lo), "v"(hi));
    return r;
}
__device__ __forceinline__ unsigned short cvt1bf(float x) {
    return (unsigned short)(pkbf(x, x) & 0xffffu);
}
// fast sigmoid/silu: v_exp + v_rcp (no IEEE divide sequence)
__device__ __forceinline__ float sigf(float x) {
    return __builtin_amdgcn_rcpf(1.f + __expf(-x));
}
__device__ __forceinline__ float siluf(float x) { return x * sigf(x); }

// elementwise silu(bf16x2 a + bf16x2 b) -> bf16x2
__device__ __forceinline__ unsigned silu2(unsigned a, unsigned b) {
    float lo = lo16(a) + lo16(b);
    float hi = hi16(a) + hi16(b);
    return pkbf(siluf(lo), siluf(hi));
}
// elementwise silu(bf16x2) -> bf16x2
__device__ __forceinline__ unsigned silu1(unsigned a) {
    return pkbf(siluf(lo16(a)), siluf(hi16(a)));
}

// packed bf16x2 atomic add (CDNA4 global_atomic_pk_add_bf16), fire-and-forget
__device__ __forceinline__ void atomic_pk_bf16(void* addr, unsigned data) {
    asm volatile("global_atomic_pk_add_bf16 %0, %1, off"
                 :: "v"((unsigned long long)(uintptr_t)addr), "v"(data) : "memory");
}

// async global->LDS, 16B per lane. LDS dest = wave-uniform base + lane*16.
__device__ __forceinline__ void load_lds16(const void* g, void* ldsbase, int lane) {
    __builtin_amdgcn_global_load_lds(
        (const __attribute__((address_space(1))) unsigned int*)(uintptr_t)g,
        (__attribute__((address_space(3))) unsigned int*)(uintptr_t)ldsbase,
        16, 0, 0);
}

// ---------------------------------------------------------------------------
// Weight prep: fp32 (fin x 128) -> bf16 MFMA B-fragment order.
// ---------------------------------------------------------------------------
struct PrepArgs {
    const float* src[14];
    int dstoff[14];
    int fin[14];
    int ktc[14];
    int tend[14];
};

__global__ void prep_kernel(PrepArgs pa, unsigned short* __restrict__ wb) {
    int tile = blockIdx.x;
    int m = 0;
    while (tile >= pa.tend[m]) m++;
    int local = tile - (m == 0 ? 0 : pa.tend[m - 1]);
    int ktc = pa.ktc[m];
    int ct = local / ktc;
    int kt = local % ktc;
    int l = threadIdx.x;   // 64
    unsigned short* dst = wb + pa.dstoff[m] + (size_t)local * 512 + l * 8;
    const float* src = pa.src[m];
    int fin = pa.fin[m];
    int col = ct * 16 + (l & 15);
#pragma unroll
    for (int i = 0; i < 8; i++) {
        int k = kt * 32 + (l >> 4) * 8 + i;
        float v = (k < fin) ? src[(size_t)k * CDIM + col] : 0.f;
        dst[i] = f2bf(v);
    }
}

// ---------------------------------------------------------------------------
// CSR build: histogram -> 3-phase multi-block scan -> rank (perm + pair)
// ---------------------------------------------------------------------------
__global__ void hist4_kernel(const int* __restrict__ r0, const int* __restrict__ r1,
                             const int* __restrict__ r2, const int* __restrict__ r3,
                             int E0, int E1, int E2, int E3, int* __restrict__ bins) {
    int i = blockIdx.x * blockDim.x + threadIdx.x;
    const int c1 = E0, c2 = c1 + E1, c3 = c2 + E2, c4 = c3 + E3;
    if (i >= c4) return;
    const int* r; int* b; int j;
    if (i < c1)      { r = r0; j = i;      b = bins; }
    else if (i < c2) { r = r1; j = i - c1; b = bins + (size_t)NCELLS; }
    else if (i < c3) { r = r2; j = i - c2; b = bins + (size_t)2 * NCELLS; }
    else             { r = r3; j = i - c3; b = bins + (size_t)3 * NCELLS; }
    atomicAdd(&b[r[j]], 1);
}

// phase 1: per-chunk sums. grid = 4*nchunk, block = 256.
__global__ void scan_sum_kernel(const int* __restrict__ bins, int* __restrict__ part,
                                int NB, int nchunk) {
    const int rel = blockIdx.x / nchunk;
    const int ch  = blockIdx.x % nchunk;
    const int t = threadIdx.x;
    const int base = ch * SCHUNK;
    const int* b = bins + (size_t)rel * NB + base;
    const int lim = (NB - base < SCHUNK) ? (NB - base) : SCHUNK;
    int s = 0;
    for (int i = t; i < lim; i += 256) s += b[i];
#pragma unroll
    for (int d = 1; d < 64; d <<= 1) s += __shfl_xor(s, (unsigned)d, 64);
    __shared__ int ws[4];
    if ((t & 63) == 0) ws[t >> 6] = s;
    __syncthreads();
    if (t == 0) part[rel * nchunk + ch] = ws[0] + ws[1] + ws[2] + ws[3];
}

// phase 2: exclusive scan over partials per rel; write total to offs[NB].
__global__ void scan_part_kernel(int* __restrict__ part, int* __restrict__ offs,
                                 int NB, int nchunk) {
    const int rel = blockIdx.x;
    const int t = threadIdx.x;
    const int lane = t & 63, w = t >> 6;
    int v = (t < nchunk) ? part[rel * nchunk + t] : 0;
    int x = v;
#pragma unroll
    for (int d = 1; d < 64; d <<= 1) {
        int y = __shfl_up(x, (unsigned)d, 64);
        if (lane >= d) x += y;
    }
    __shared__ int wsum[2];
    if (lane == 63) wsum[w] = x;
    __syncthreads();
    if (w == 1) x += wsum[0];
    if (t < nchunk) part[rel * nchunk + t] = x - v;
    if (t == nchunk - 1) offs[(size_t)rel * (NB + 1) + NB] = x;
}

// phase 3: in-block exclusive scan + chunk offset. grid = 4*nchunk, block = 256.
__global__ void scan_write_kernel(const int* __restrict__ bins, const int* __restrict__ part,
                                  int* __restrict__ offs, int NB, int nchunk) {
    const int rel = blockIdx.x / nchunk;
    const int ch  = blockIdx.x % nchunk;
    const int t = threadIdx.x;
    const int lane = t & 63, w = t >> 6;
    const int base = ch * SCHUNK;
    const int* b = bins + (size_t)rel * NB + base;
    int* o = offs + (size_t)rel * (NB + 1) + base;
    const int lim = (NB - base < SCHUNK) ? (NB - base) : SCHUNK;
    const int i0 = t * 4;
    int v[4];
#pragma unroll
    for (int k = 0; k < 4; k++) v[k] = (i0 + k < lim) ? b[i0 + k] : 0;
    const int tsum = v[0] + v[1] + v[2] + v[3];
    int x = tsum;
#pragma unroll
    for (int d = 1; d < 64; d <<= 1) {
        int y = __shfl_up(x, (unsigned)d, 64);
        if (lane >= d) x += y;
    }
    __shared__ int wsum[4];
    if (lane == 63) wsum[w] = x;
    __syncthreads();
    int woff = 0;
#pragma unroll
    for (int k = 0; k < 4; k++) if (k < w) woff += wsum[k];
    int excl = woff + x - tsum + part[rel * nchunk + ch];
#pragma unroll
    for (int k = 0; k < 4; k++) {
        if (i0 + k < lim) { o[i0 + k] = excl; excl += v[k]; }
    }
}

struct RankArgs {
    const int* send[4];
    const int* recv[4];
    int*  perm[4];
    int2* pair[4];
    int E[4];
    const int* offs;   // 4*(NCELLS+1)
    int*       cur;    // 4*NCELLS
};

__global__ void rank4p_kernel(RankArgs a) {
    int i = blockIdx.x * blockDim.x + threadIdx.x;
    int rel = 0, j = i;
    while (rel < 4 && j >= a.E[rel]) { j -= a.E[rel]; rel++; }
    if (rel >= 4) return;
    int v = a.recv[rel][j];
    int p = a.offs[(size_t)rel * (NCELLS + 1) + v] +
            atomicAdd(&a.cur[(size_t)rel * NCELLS + v], 1);
    a.perm[rel][p] = j;
    a.pair[rel][p] = make_int2(a.send[rel][j], v);
}

// ---------------------------------------------------------------------------
// P-GEMM pair.
// ---------------------------------------------------------------------------
template <bool SAME>
__global__ __launch_bounds__(256, 4)
void pgemm2_kernel(const float* __restrict__ fA, const float* __restrict__ fB,
                   const unsigned short* __restrict__ W1T, const float* __restrict__ b1,
                   unsigned short* __restrict__ PA, unsigned short* __restrict__ PB,
                   int nblk)
{
    constexpr int AS = 136;
    __shared__ unsigned short A[64 * AS];

    const bool second = !SAME && ((int)blockIdx.x >= nblk);
    const float* f = second ? fB : fA;
    const int n0 = (second ? (int)blockIdx.x - nblk : (int)blockIdx.x) * 64;

    const int t = threadIdx.x;
    {
        const int rl = t >> 2, q = t & 3;
        int n = n0 + rl; n = (n < NCELLS) ? n : (NCELLS - 1);
        const float4* sp = (const float4*)(f + (size_t)n * CDIM + q * 32);
        unsigned short* arow = A + rl * AS + q * 32;
#pragma unroll
        for (int i = 0; i < 4; i++) {
            float4 a = sp[2 * i], b = sp[2 * i + 1];
            uint4 o;
            o.x = pkbf(a.x, a.y); o.y = pkbf(a.z, a.w);
            o.z = pkbf(b.x, b.y); o.w = pkbf(b.z, b.w);
            *(uint4*)(arow + i * 8) = o;
        }
    }
    __syncthreads();

    const int l = t & 63, w = t >> 6;
    const int lr = l & 15, lg = l >> 4;
    const int wr = (w & 1) * 32, wc = (w >> 1) * 64;

    const int nhalf = SAME ? 2 : 1;
#pragma unroll
    for (int h = 0; h < nhalf; h++) {
        const bool hiHalf = SAME ? (h == 1) : second;
        const int koff = hiHalf ? 4 : 0;
        unsigned short* P = hiHalf ? PB : PA;

        f32x4 acc[2][4];
#pragma unroll
        for (int mt = 0; mt < 2; mt++)
#pragma unroll
            for (int ct = 0; ct < 4; ct++) acc[mt][ct] = (f32x4){0.f, 0.f, 0.f, 0.f};

#pragma unroll
        for (int kt = 0; kt < 4; ++kt) {
            short8 av[2];
#pragma unroll
            for (int mt = 0; mt < 2; mt++)
                av[mt] = *(const short8*)(A + (wr + mt * 16 + lr) * AS + kt * 32 + lg * 8);
#pragma unroll
            for (int ct = 0; ct < 4; ct++) {
                const int cg = (wc >> 4) + ct;
                short8 bv = *(const short8*)(W1T + ((size_t)(cg * 9 + kt + koff) * 64 + l) * 8);
                acc[0][ct] = __builtin_amdgcn_mfma_f32_16x16x32_bf16(av[0], bv, acc[0][ct], 0, 0, 0);
                acc[1][ct] = __builtin_amdgcn_mfma_f32_16x16x32_bf16(av[1], bv, acc[1][ct], 0, 0, 0);
            }
        }

        float b1c[4];
#pragma unroll
        for (int ct = 0; ct < 4; ct++) b1c[ct] = hiHalf ? b1[wc + ct * 16 + lr] : 0.f;

#pragma unroll
        for (int mt = 0; mt < 2; mt++)
#pragma unroll
            for (int j = 0; j < 4; j++) {
                const int row = wr + mt * 16 + lg * 4 + j;
                const int n2  = n0 + row;
                if (n2 < NCELLS) {
#pragma unroll
                    for (int ct = 0; ct < 4; ct++)
                        P[(size_t)n2 * CDIM + wc + ct * 16 + lr] = cvt1bf(acc[mt][ct][j] + b1c[ct]);
                }
            }
    }
}

// ---------------------------------------------------------------------------
// EConv (r14 core + XCD-chunked block swizzle): consecutive sorted-edge
// blocks share Pt/acc locality, so map contiguous block chunks to one XCD
// (bijective m204 form) to keep each XCD's L2 on ~1/8 of the Pt table.
// ---------------------------------------------------------------------------
template <int NINV>
__global__ __launch_bounds__(256, 4)
void econv_kernel(const unsigned short* __restrict__ Ps, const unsigned short* __restrict__ Pt,
                  const int* __restrict__ perm, const int2* __restrict__ pair,
                  const float* __restrict__ inv,
                  const unsigned short* __restrict__ W1T,
                  const unsigned short* __restrict__ W2T, const float* __restrict__ b2,
                  const float* __restrict__ Wg, const float* __restrict__ bg,
                  unsigned short* __restrict__ acc, int E)
{
    __shared__ unsigned short PsL[64 * 128];   // also Y (in-place)
    __shared__ unsigned short PtL[64 * 128];   // also O
    __shared__ unsigned short Ainv[64 * 40];
    __shared__ int cellid[64];

    const int t = threadIdx.x, l = t & 63, w = t >> 6;
    // XCD-chunked bijective block swizzle (T1 / m204)
    int bid;
    {
        const int nwg = gridDim.x;
        const int orig = blockIdx.x;
        const int xcd = orig & 7, idx = orig >> 3;
        const int q = nwg >> 3, r = nwg & 7;
        bid = (xcd < r ? xcd * (q + 1) : r * (q + 1) + (xcd - r) * q) + idx;
    }
    const int e0 = bid * 64;
    const int base = w * 16;
    const int lr = l & 15, lg = l >> 4;

    // ---- async stage (wave-local rows base..base+15) ----
    {
        const int slot = l & 15;
        const int rsub = l >> 4;
#pragma unroll
        for (int i = 0; i < 4; i++) {
            const int r = base + i * 4 + rsub;
            int p = e0 + r; p = (p < E) ? p : (E - 1);
            const int2 sr = pair[p];
            const int ss = slot ^ (r & 7);
            load_lds16(Ps + (size_t)sr.x * CDIM + ss * 8, PsL + (base + i * 4) * 128, l);
            load_lds16(Pt + (size_t)sr.y * CDIM + ss * 8, PtL + (base + i * 4) * 128, l);
        }
    }
    // ---- cellid + Ainv (uint4 per lane; lanes<16 of each wave convert inv) ----
    {
        const int r = base + lr;
        uint4 u = make_uint4(0u, 0u, 0u, 0u);
        if (lg == 0) {
            int p = e0 + r; p = (p < E) ? p : (E - 1);
            const int j = perm[p];
            cellid[r] = pair[p].y;
            const float* ip = inv + (size_t)j * NINV;
            float v[8];
#pragma unroll
            for (int k = 0; k < 8; k++) v[k] = (k < NINV) ? ip[k] : 0.f;
            u.x = pkbf(v[0], v[1]);
            u.y = pkbf(v[2], v[3]);
            u.z = pkbf(v[4], v[5]);
            u.w = pkbf(v[6], v[7]);
        }
        *(uint4*)(Ainv + r * 40 + lg * 8) = u;
    }
    // drain this wave's global_load_lds (no block barrier)
    asm volatile("s_waitcnt vmcnt(0)" ::: "memory");

    // ---- inv MFMA: rows base..base+15, cols 0..127 (8 frags) ----
    f32x4 a1[8];
#pragma unroll
    for (int cg = 0; cg < 8; cg++) a1[cg] = (f32x4){0.f, 0.f, 0.f, 0.f};
    {
        short8 av = *(const short8*)(Ainv + (base + lr) * 40 + lg * 8);
#pragma unroll
        for (int cg = 0; cg < 8; cg++) {
            short8 bv = *(const short8*)(W1T + ((size_t)(cg * 9 + 8) * 64 + l) * 8);
            a1[cg] = __builtin_amdgcn_mfma_f32_16x16x32_bf16(av, bv, a1[cg], 0, 0, 0);
        }
    }

    // ---- phase A: PtL += a1 (scalar RMW, wave-local) ----
#pragma unroll
    for (int cg = 0; cg < 8; cg++) {
        const int col = cg * 16 + lr;
#pragma unroll
        for (int j = 0; j < 4; j++) {
            const int row = base + lg * 4 + j;
            const int idx = row * 128 + (col ^ ((row & 7) << 3));
            PtL[idx] = cvt1bf(bf2f(PtL[idx]) + a1[cg][j]);
        }
    }

    // ---- phase B: y = silu(Ps + Pt') vectorized, in place (wave-local) ----
    {
        const int rl = base + (l >> 2), q = l & 3;
        unsigned short* psrow = PsL + rl * 128;
        const unsigned short* ptrow = PtL + rl * 128;
#pragma unroll
        for (int i = 0; i < 4; i++) {
            const int sl = ((q * 4 + i) ^ (rl & 7)) * 8;
            uint4 us = *(const uint4*)(psrow + sl);
            uint4 ut = *(const uint4*)(ptrow + sl);
            uint4 o;
            o.x = silu2(us.x, ut.x);
            o.y = silu2(us.y, ut.y);
            o.z = silu2(us.z, ut.z);
            o.w = silu2(us.w, ut.w);
            *(uint4*)(psrow + sl) = o;
        }
    }

    // ---- layer 2: rows base+lr, all 128 cols (8 frags) ----
    f32x4 a2[8];
#pragma unroll
    for (int cg = 0; cg < 8; cg++) a2[cg] = (f32x4){0.f, 0.f, 0.f, 0.f};
#pragma unroll
    for (int kt = 0; kt < 4; ++kt) {
        const int row = base + lr;
        const int sl  = (kt * 4 + lg) ^ (row & 7);
        short8 av = *(const short8*)(PsL + row * 128 + sl * 8);
#pragma unroll
        for (int cg = 0; cg < 8; cg++) {
            short8 bv = *(const short8*)(W2T + ((size_t)(cg * 4 + kt) * 64 + l) * 8);
            a2[cg] = __builtin_amdgcn_mfma_f32_16x16x32_bf16(av, bv, a2[cg], 0, 0, 0);
        }
    }

    // ---- silu + gate (wave-local shfl reduce over lr) ----
    float wg[8], b2c[8];
#pragma unroll
    for (int cg = 0; cg < 8; cg++) {
        const int col = cg * 16 + lr;
        wg[cg]  = Wg[col];
        b2c[cg] = b2[col];
    }
#pragma unroll
    for (int cg = 0; cg < 8; cg++)
#pragma unroll
        for (int j = 0; j < 4; j++)
            a2[cg][j] = siluf(a2[cg][j] + b2c[cg]);

    const float bgs = bg[0];
    float g4[4];
#pragma unroll
    for (int j = 0; j < 4; j++) {
        float p = 0.f;
#pragma unroll
        for (int cg = 0; cg < 8; cg++) p += a2[cg][j] * wg[cg];
        p += __shfl_xor(p, 1, 16);
        p += __shfl_xor(p, 2, 16);
        p += __shfl_xor(p, 4, 16);
        p += __shfl_xor(p, 8, 16);
        const int row = base + lg * 4 + j;
        g4[j] = (e0 + row < E) ? sigf(p + bgs) : 0.f;
    }

    // ---- O-stage into PtL (wave-local) ----
#pragma unroll
    for (int cg = 0; cg < 8; cg++) {
        const int col = cg * 16 + lr;
#pragma unroll
        for (int j = 0; j < 4; j++) {
            const int row = base + lg * 4 + j;
            PtL[row * 128 + (col ^ ((row & 7) << 3))] = cvt1bf(a2[cg][j] * g4[j]);
        }
    }

    // ---- wave-uniform strip-scan reduction (bf16 acc) ----
    {
        const int pidx = e0 + base - 1;
        const int nidx = e0 + base + 16;
        const int cprev = (pidx >= 0) ? pair[(pidx < E) ? pidx : (E - 1)].y : -1;
        const int cnext = (nidx < E) ? pair[nidx].y : -1;

        unsigned vv[16];
        int cid[16];
#pragma unroll
        for (int i = 0; i < 16; i++) {
            const int r = base + i;
            const unsigned* prow = (const unsigned*)(PtL + r * 128);
            vv[i]  = prow[l ^ ((r & 7) << 2)];
            cid[i] = cellid[r];
        }

        unsigned* acc32 = (unsigned*)acc;
        float accL = 0.f, accH = 0.f;
        bool openLeft = (cid[0] == cprev);
#pragma unroll
        for (int i = 0; i < 16; i++) {
            if (i > 0 && cid[i] != cid[i - 1]) {
                const size_t di = (size_t)cid[i - 1] * 64 + l;
                if (openLeft) atomic_pk_bf16(acc32 + di, pkbf(accL, accH));
                else          acc32[di] = pkbf(accL, accH);
                accL = 0.f; accH = 0.f; openLeft = false;
            }
            accL += lo16(vv[i]);
            accH += hi16(vv[i]);
        }
        const bool openRight = (cid[15] == cnext);
        const size_t di = (size_t)cid[15] * 64 + l;
        if (openLeft || openRight) atomic_pk_bf16(acc32 + di, pkbf(accL, accH));
        else                       acc32[di] = pkbf(accL, accH);
    }
}

// ---------------------------------------------------------------------------
// Update MLP: out = f + silu([f | silu(acc1) | silu(acc2)] @ W1 + b1) @ W2 + b2
// ---------------------------------------------------------------------------
template <int F>
__global__ __launch_bounds__(256, F == 3 ? 3 : 4)
void update_kernel(const float* __restrict__ f,
                   const unsigned short* __restrict__ s1, const unsigned short* __restrict__ s2,
                   const unsigned short* __restrict__ W1T, const float* __restrict__ b1,
                   const unsigned short* __restrict__ W2T, const float* __restrict__ b2,
                   float* __restrict__ out)
{
    constexpr int K   = F * CDIM;
    constexpr int KT1 = K / 32;
    constexpr int AS  = K + 8;
    constexpr int YS  = 136;
    __shared__ unsigned short U[64 * AS];   // union: A | Y
    unsigned short* Alds = U;
    unsigned short* Ylds = U;

    const int t  = threadIdx.x;
    const int n0 = blockIdx.x * 64;
    const int w = t >> 6, l = t & 63;

    // ---- phase 1: build A-tile [f | silu(s1) | silu(s2)] ----
    {
        const int rl = t >> 2, q = t & 3;
        int n = n0 + rl; n = (n < NCELLS) ? n : (NCELLS - 1);
        unsigned short* arow = Alds + rl * AS;
        {
            const float4* sp = (const float4*)(f + (size_t)n * CDIM + q * 32);
#pragma unroll
            for (int i = 0; i < 4; i++) {
                float4 a = sp[2 * i], b = sp[2 * i + 1];
                uint4 o;
                o.x = pkbf(a.x, a.y); o.y = pkbf(a.z, a.w);
                o.z = pkbf(b.x, b.y); o.w = pkbf(b.z, b.w);
                *(uint4*)(arow + q * 32 + i * 8) = o;
            }
        }
#pragma unroll
        for (int p = 1; p < F; p++) {
            const unsigned short* accp = (p == 1) ? s1 : s2;
            const uint4* sp = (const uint4*)(accp + (size_t)n * CDIM + q * 32);
            uint4* dstv = (uint4*)(arow + p * CDIM + q * 32);
#pragma unroll
            for (int i = 0; i < 4; i++) {
                uint4 v = sp[i];
                uint4 o;
                o.x = silu1(v.x); o.y = silu1(v.y);
                o.z = silu1(v.z); o.w = silu1(v.w);
                dstv[i] = o;
            }
        }
    }
    __syncthreads();

    const int lr = l & 15, lg = l >> 4;
    const int wr = (w & 1) * 32;
    const int wc = (w >> 1) * 64;

    f32x4 a1[2][4];
#pragma unroll
    for (int mt = 0; mt < 2; mt++)
#pragma unroll
        for (int ct = 0; ct < 4; ct++) a1[mt][ct] = (f32x4){0.f, 0.f, 0.f, 0.f};

    for (int kt = 0; kt < KT1; ++kt) {
        short8 av[2];
#pragma unroll
        for (int mt = 0; mt < 2; mt++)
            av[mt] = *(const short8*)(Alds + (wr + mt * 16 + lr) * AS + kt * 32 + lg * 8);
#pragma unroll
        for (int ct = 0; ct < 4; ct++) {
            const int cg = (wc >> 4) + ct;
            short8 bv = *(const short8*)(W1T + ((size_t)(cg * KT1 + kt) * 64 + l) * 8);
            a1[0][ct] = __builtin_amdgcn_mfma_f32_16x16x32_bf16(av[0], bv, a1[0][ct], 0, 0, 0);
            a1[1][ct] = __builtin_amdgcn_mfma_f32_16x16x32_bf16(av[1], bv, a1[1][ct], 0, 0, 0);
        }
    }
    __syncthreads();   // A consumed; Y overwrites

#pragma unroll
    for (int ct = 0; ct < 4; ct++) {
        const int col = wc + ct * 16 + lr;
        const float bb = b1[col];
#pragma unroll
        for (int mt = 0; mt < 2; mt++)
#pragma unroll
            for (int j = 0; j < 4; j++) {
                const int row = wr + mt * 16 + lg * 4 + j;
                Ylds[row * YS + col] = cvt1bf(siluf(a1[mt][ct][j] + bb));
            }
    }
    __syncthreads();

    f32x4 a2[2][4];
#pragma unroll
    for (int mt = 0; mt < 2; mt++)
#pragma unroll
        for (int ct = 0; ct < 4; ct++) a2[mt][ct] = (f32x4){0.f, 0.f, 0.f, 0.f};

    for (int kt = 0; kt < 4; ++kt) {
        short8 av[2];
#pragma unroll
        for (int mt = 0; mt < 2; mt++)
            av[mt] = *(const short8*)(Ylds + (wr + mt * 16 + lr) * YS + kt * 32 + lg * 8);
#pragma unroll
        for (int ct = 0; ct < 4; ct++) {
            const int cg = (wc >> 4) + ct;
            short8 bv = *(const short8*)(W2T + ((size_t)(cg * 4 + kt) * 64 + l) * 8);
            a2[0][ct] = __builtin_amdgcn_mfma_f32_16x16x32_bf16(av[0], bv, a2[0][ct], 0, 0, 0);
            a2[1][ct] = __builtin_amdgcn_mfma_f32_16x16x32_bf16(av[1], bv, a2[1][ct], 0, 0, 0);
        }
    }

    float b2c[4];
#pragma unroll
    for (int ct = 0; ct < 4; ct++) b2c[ct] = b2[wc + ct * 16 + lr];

#pragma unroll
    for (int mt = 0; mt < 2; mt++)
#pragma unroll
        for (int j = 0; j < 4; j++) {
            const int row = wr + mt * 16 + lg * 4 + j;
            const int n2  = n0 + row;
            if (n2 < NCELLS) {
#pragma unroll
                for (int ct = 0; ct < 4; ct++) {
                    const int col = wc + ct * 16 + lr;
                    out[(size_t)n2 * CDIM + col] =
                        f[(size_t)n2 * CDIM + col] + a2[mt][ct][j] + b2c[ct];
                }
            }
        }
}

// ---------------------------------------------------------------------------
extern "C" void kernel_launch(void* const* d_in, const int* in_sizes, int n_in,
                              void* d_out, int out_size, void* d_ws, size_t ws_size,
                              hipStream_t stream)
{
    const float* f0 = (const float*)d_in[0];
    const float* f1 = (const float*)d_in[1];
    const float* f2 = (const float*)d_in[2];

    const int*   a0_send = (const int*)d_in[3];
    const int*   a0_recv = (const int*)d_in[4];
    const float* inv_a0  = (const float*)d_in[5];
    const float* a0_b1   = (const float*)d_in[7];
    const float* a0_b2   = (const float*)d_in[9];
    const float* a0_Wg   = (const float*)d_in[10];
    const float* a0_bg   = (const float*)d_in[11];

    const int*   a1_send = (const int*)d_in[12];
    const int*   a1_recv = (const int*)d_in[13];
    const float* inv_a1  = (const float*)d_in[14];
    const float* a1_b1   = (const float*)d_in[16];
    const float* a1_b2   = (const float*)d_in[18];
    const float* a1_Wg   = (const float*)d_in[19];
    const float* a1_bg   = (const float*)d_in[20];

    const int*   i1_send = (const int*)d_in[21];
    const int*   i1_recv = (const int*)d_in[22];
    const float* inv_i1  = (const float*)d_in[23];
    const float* i1_b1   = (const float*)d_in[25];
    const float* i1_b2   = (const float*)d_in[27];
    const float* i1_Wg   = (const float*)d_in[28];
    const float* i1_bg   = (const float*)d_in[29];

    const int*   i2_send = (const int*)d_in[30];
    const int*   i2_recv = (const int*)d_in[31];
    const float* inv_i2  = (const float*)d_in[32];
    const float* i2_b1   = (const float*)d_in[34];
    const float* i2_b2   = (const float*)d_in[36];
    const float* i2_Wg   = (const float*)d_in[37];
    const float* i2_bg   = (const float*)d_in[38];

    const float* u0_b1 = (const float*)d_in[40];
    const float* u0_b2 = (const float*)d_in[42];
    const float* u1_b1 = (const float*)d_in[44];
    const float* u1_b2 = (const float*)d_in[46];
    const float* u2_b1 = (const float*)d_in[48];
    const float* u2_b2 = (const float*)d_in[50];

    const int E_a0 = in_sizes[3];
    const int E_a1 = in_sizes[12];
    const int E_i1 = in_sizes[21];
    const int E_i2 = in_sizes[30];
    const int Es[4] = {E_a0, E_a1, E_i1, E_i2};

    // ---- ws bump allocator ----
    char* base = (char*)d_ws;
    size_t off = 0;
    auto alloc = [&](size_t bytes) -> char* {
        off = (off + 255) & ~(size_t)255;
        char* p = base + off;
        off += bytes;
        return p;
    };
    unsigned short* wb  = (unsigned short*)alloc(753664);
    int* offs_all = (int*)alloc((size_t)4 * (NCELLS + 1) * sizeof(int));
    int* bins_all = (int*)alloc((size_t)4 * NCELLS * sizeof(int));   // also cursor
    const int nchunk = (NCELLS + SCHUNK - 1) / SCHUNK;
    int* part = (int*)alloc((size_t)4 * nchunk * sizeof(int));
    int* perm[4];
    int2* pair[4];
    for (int r = 0; r < 4; r++) {
        perm[r] = (int*)alloc((size_t)Es[r] * sizeof(int));
        pair[r] = (int2*)alloc((size_t)Es[r] * sizeof(int2));
    }
    // 4 independent acc buffers: all zeroed upfront, no mid-stream re-zeroes
    unsigned short* acc0 = (unsigned short*)alloc((size_t)NCELLS * CDIM * sizeof(unsigned short));
    unsigned short* acc1 = (unsigned short*)alloc((size_t)NCELLS * CDIM * sizeof(unsigned short));
    unsigned short* acc2 = (unsigned short*)alloc((size_t)NCELLS * CDIM * sizeof(unsigned short));
    unsigned short* acc3 = (unsigned short*)alloc((size_t)NCELLS * CDIM * sizeof(unsigned short));
    unsigned short* PsT = (unsigned short*)alloc((size_t)NCELLS * CDIM * sizeof(unsigned short));
    unsigned short* PtT = (unsigned short*)alloc((size_t)NCELLS * CDIM * sizeof(unsigned short));

    // ---- weight prep ----
    const int o_w1[4]  = {0, 36864, 73728, 110592};
    const int o_w2[4]  = {147456, 163840, 180224, 196608};
    const int o_uw1[3] = {212992, 245760, 294912};
    const int o_uw2[3] = {327680, 344064, 360448};

    PrepArgs pa;
    int idx = 0, cum = 0;
    auto add = [&](const void* s, int fin, int ktc, int woff) {
        pa.src[idx] = (const float*)s; pa.fin[idx] = fin; pa.ktc[idx] = ktc;
        pa.dstoff[idx] = woff; cum += ktc * 8; pa.tend[idx] = cum; idx++;
    };
    add(d_in[6],  259, 9,  o_w1[0]);
    add(d_in[15], 262, 9,  o_w1[1]);
    add(d_in[24], 259, 9,  o_w1[2]);
    add(d_in[33], 262, 9,  o_w1[3]);
    add(d_in[8],  128, 4,  o_w2[0]);
    add(d_in[17], 128, 4,  o_w2[1]);
    add(d_in[26], 128, 4,  o_w2[2]);
    add(d_in[35], 128, 4,  o_w2[3]);
    add(d_in[39], 256, 8,  o_uw1[0]);
    add(d_in[43], 384, 12, o_uw1[1]);
    add(d_in[47], 256, 8,  o_uw1[2]);
    add(d_in[41], 128, 4,  o_uw2[0]);
    add(d_in[45], 128, 4,  o_uw2[1]);
    add(d_in[49], 128, 4,  o_uw2[2]);
    prep_kernel<<<cum, 64, 0, stream>>>(pa, wb);

    // ---- CSR build: hist -> 3-phase scan -> rank ----
    const int Etot = E_a0 + E_a1 + E_i1 + E_i2;
    hipMemsetAsync(bins_all, 0, (size_t)4 * NCELLS * sizeof(int), stream);
    hist4_kernel<<<(Etot + 255) / 256, 256, 0, stream>>>(
        a0_recv, a1_recv, i1_recv, i2_recv, E_a0, E_a1, E_i1, E_i2, bins_all);
    scan_sum_kernel<<<4 * nchunk, 256, 0, stream>>>(bins_all, part, NCELLS, nchunk);
    scan_part_kernel<<<4, 128, 0, stream>>>(part, offs_all, NCELLS, nchunk);
    scan_write_kernel<<<4 * nchunk, 256, 0, stream>>>(bins_all, part, offs_all, NCELLS, nchunk);
    hipMemsetAsync(bins_all, 0, (size_t)4 * NCELLS * sizeof(int), stream);
    {
        RankArgs ra;
        const int* sends[4] = {a0_send, a1_send, i1_send, i2_send};
        const int* recvs[4] = {a0_recv, a1_recv, i1_recv, i2_recv};
        for (int r = 0; r < 4; r++) {
            ra.send[r] = sends[r]; ra.recv[r] = recvs[r];
            ra.perm[r] = perm[r]; ra.pair[r] = pair[r]; ra.E[r] = Es[r];
        }
        ra.offs = offs_all; ra.cur = bins_all;
        rank4p_kernel<<<(Etot + 255) / 256, 256, 0, stream>>>(ra);
    }

    const size_t accBytes = (size_t)NCELLS * CDIM * sizeof(unsigned short);
    hipMemsetAsync(acc0, 0, accBytes, stream);
    hipMemsetAsync(acc1, 0, accBytes, stream);
    hipMemsetAsync(acc2, 0, accBytes, stream);
    hipMemsetAsync(acc3, 0, accBytes, stream);

    float* out = (float*)d_out;
    const int UPD_BLK = (NCELLS + 63) / 64;
    const int PG_BLK  = UPD_BLK;

    // rank 0: a0 -> acc0
    pgemm2_kernel<true><<<PG_BLK, 256, 0, stream>>>(
        f0, f0, wb + o_w1[0], a0_b1, PsT, PtT, PG_BLK);
    econv_kernel<3><<<(E_a0 + 63) / 64, 256, 0, stream>>>(
        PsT, PtT, perm[0], pair[0], inv_a0,
        wb + o_w1[0], wb + o_w2[0], a0_b2, a0_Wg, a0_bg, acc0, E_a0);
    update_kernel<2><<<UPD_BLK, 256, 0, stream>>>(
        f0, acc0, nullptr, wb + o_uw1[0], u0_b1, wb + o_uw2[0], u0_b2, out);

    // rank 1: a1 -> acc1, i1 -> acc2
    pgemm2_kernel<true><<<PG_BLK, 256, 0, stream>>>(
        f1, f1, wb + o_w1[1], a1_b1, PsT, PtT, PG_BLK);
    econv_kernel<6><<<(E_a1 + 63) / 64, 256, 0, stream>>>(
        PsT, PtT, perm[1], pair[1], inv_a1,
        wb + o_w1[1], wb + o_w2[1], a1_b2, a1_Wg, a1_bg, acc1, E_a1);
    pgemm2_kernel<false><<<2 * PG_BLK, 256, 0, stream>>>(
        f0, f1, wb + o_w1[2], i1_b1, PsT, PtT, PG_BLK);
    econv_kernel<3><<<(E_i1 + 63) / 64, 256, 0, stream>>>(
        PsT, PtT, perm[2], pair[2], inv_i1,
        wb + o_w1[2], wb + o_w2[2], i1_b2, i1_Wg, i1_bg, acc2, E_i1);
    update_kernel<3><<<UPD_BLK, 256, 0, stream>>>(
        f1, acc1, acc2, wb + o_uw1[1], u1_b1, wb + o_uw2[1], u1_b2,
        out + (size_t)NCELLS * CDIM);

    // rank 2: i2 -> acc3
    pgemm2_kernel<false><<<2 * PG_BLK, 256, 0, stream>>>(
        f1, f2, wb + o_w1[3], i2_b1, PsT, PtT, PG_BLK);
    econv_kernel<6><<<(E_i2 + 63) / 64, 256, 0, stream>>>(
        PsT, PtT, perm[3], pair[3], inv_i2,
        wb + o_w1[3], wb + o_w2[3], i2_b2, i2_Wg, i2_bg, acc3, E_i2);
    update_kernel<2><<<UPD_BLK, 256, 0, stream>>>(
        f2, acc3, nullptr, wb + o_uw1[2], u2_b1, wb + o_uw2[2], u2_b2,
        out + 2 * (size_t)NCELLS * CDIM);
}

// Round 19
// 715.280 us; speedup vs baseline: 1.1380x; 1.1380x over previous
//
#include <hip/hip_runtime.h>
#include <hip/hip_bf16.h>
#include <cstdint>
#include <cstddef>

#define CDIM 128
#define NCELLS 100000
#define SCHUNK 1024

typedef __attribute__((ext_vector_type(8))) short short8;
typedef __attribute__((ext_vector_type(4))) float f32x4;

__device__ __forceinline__ unsigned short f2bf(float f) {
    unsigned u = __float_as_uint(f);
    unsigned r = u + 0x7FFFu + ((u >> 16) & 1u);
    return (unsigned short)(r >> 16);
}
__device__ __forceinline__ float bf2f(unsigned short u) {
    return __uint_as_float(((unsigned)u) << 16);
}
__device__ __forceinline__ float lo16(unsigned u) { return __uint_as_float(u << 16); }
__device__ __forceinline__ float hi16(unsigned u) { return __uint_as_float(u & 0xffff0000u); }
// packed f32x2 -> bf16x2 (1 instr, RNE)
__device__ __forceinline__ unsigned pkbf(float lo, float hi) {
    unsigned r;
    asm("v_cvt_pk_bf16_f32 %0, %1, %2" : "=v"(r) : "v"(lo), "v"(hi));
    return r;
}
__device__ __forceinline__ unsigned short cvt1bf(float x) {
    return (unsigned short)(pkbf(x, x) & 0xffffu);
}
// fast sigmoid/silu: v_exp + v_rcp (no IEEE divide sequence)
__device__ __forceinline__ float sigf(float x) {
    return __builtin_amdgcn_rcpf(1.f + __expf(-x));
}
__device__ __forceinline__ float siluf(float x) { return x * sigf(x); }

// elementwise silu(bf16x2 a + bf16x2 b) -> bf16x2
__device__ __forceinline__ unsigned silu2(unsigned a, unsigned b) {
    float lo = lo16(a) + lo16(b);
    float hi = hi16(a) + hi16(b);
    return pkbf(siluf(lo), siluf(hi));
}
// elementwise silu(bf16x2) -> bf16x2
__device__ __forceinline__ unsigned silu1(unsigned a) {
    return pkbf(siluf(lo16(a)), siluf(hi16(a)));
}

// packed bf16x2 atomic add (CDNA4 global_atomic_pk_add_bf16), fire-and-forget
__device__ __forceinline__ void atomic_pk_bf16(void* addr, unsigned data) {
    asm volatile("global_atomic_pk_add_bf16 %0, %1, off"
                 :: "v"((unsigned long long)(uintptr_t)addr), "v"(data) : "memory");
}

// async global->LDS, 16B per lane. LDS dest = wave-uniform base + lane*16.
__device__ __forceinline__ void load_lds16(const void* g, void* ldsbase, int lane) {
    __builtin_amdgcn_global_load_lds(
        (const __attribute__((address_space(1))) unsigned int*)(uintptr_t)g,
        (__attribute__((address_space(3))) unsigned int*)(uintptr_t)ldsbase,
        16, 0, 0);
}

// ---------------------------------------------------------------------------
// Weight prep: fp32 (fin x 128) -> bf16 MFMA B-fragment order.
// ---------------------------------------------------------------------------
struct PrepArgs {
    const float* src[14];
    int dstoff[14];
    int fin[14];
    int ktc[14];
    int tend[14];
};

__global__ void prep_kernel(PrepArgs pa, unsigned short* __restrict__ wb) {
    int tile = blockIdx.x;
    int m = 0;
    while (tile >= pa.tend[m]) m++;
    int local = tile - (m == 0 ? 0 : pa.tend[m - 1]);
    int ktc = pa.ktc[m];
    int ct = local / ktc;
    int kt = local % ktc;
    int l = threadIdx.x;   // 64
    unsigned short* dst = wb + pa.dstoff[m] + (size_t)local * 512 + l * 8;
    const float* src = pa.src[m];
    int fin = pa.fin[m];
    int col = ct * 16 + (l & 15);
#pragma unroll
    for (int i = 0; i < 8; i++) {
        int k = kt * 32 + (l >> 4) * 8 + i;
        float v = (k < fin) ? src[(size_t)k * CDIM + col] : 0.f;
        dst[i] = f2bf(v);
    }
}

// ---------------------------------------------------------------------------
// CSR build: histogram -> 3-phase multi-block scan -> rank (perm + pair)
// ---------------------------------------------------------------------------
__global__ void hist4_kernel(const int* __restrict__ r0, const int* __restrict__ r1,
                             const int* __restrict__ r2, const int* __restrict__ r3,
                             int E0, int E1, int E2, int E3, int* __restrict__ bins) {
    int i = blockIdx.x * blockDim.x + threadIdx.x;
    const int c1 = E0, c2 = c1 + E1, c3 = c2 + E2, c4 = c3 + E3;
    if (i >= c4) return;
    const int* r; int* b; int j;
    if (i < c1)      { r = r0; j = i;      b = bins; }
    else if (i < c2) { r = r1; j = i - c1; b = bins + (size_t)NCELLS; }
    else if (i < c3) { r = r2; j = i - c2; b = bins + (size_t)2 * NCELLS; }
    else             { r = r3; j = i - c3; b = bins + (size_t)3 * NCELLS; }
    atomicAdd(&b[r[j]], 1);
}

// phase 1: per-chunk sums. grid = 4*nchunk, block = 256.
__global__ void scan_sum_kernel(const int* __restrict__ bins, int* __restrict__ part,
                                int NB, int nchunk) {
    const int rel = blockIdx.x / nchunk;
    const int ch  = blockIdx.x % nchunk;
    const int t = threadIdx.x;
    const int base = ch * SCHUNK;
    const int* b = bins + (size_t)rel * NB + base;
    const int lim = (NB - base < SCHUNK) ? (NB - base) : SCHUNK;
    int s = 0;
    for (int i = t; i < lim; i += 256) s += b[i];
#pragma unroll
    for (int d = 1; d < 64; d <<= 1) s += __shfl_xor(s, (unsigned)d, 64);
    __shared__ int ws[4];
    if ((t & 63) == 0) ws[t >> 6] = s;
    __syncthreads();
    if (t == 0) part[rel * nchunk + ch] = ws[0] + ws[1] + ws[2] + ws[3];
}

// phase 2: exclusive scan over partials per rel; write total to offs[NB].
__global__ void scan_part_kernel(int* __restrict__ part, int* __restrict__ offs,
                                 int NB, int nchunk) {
    const int rel = blockIdx.x;
    const int t = threadIdx.x;
    const int lane = t & 63, w = t >> 6;
    int v = (t < nchunk) ? part[rel * nchunk + t] : 0;
    int x = v;
#pragma unroll
    for (int d = 1; d < 64; d <<= 1) {
        int y = __shfl_up(x, (unsigned)d, 64);
        if (lane >= d) x += y;
    }
    __shared__ int wsum[2];
    if (lane == 63) wsum[w] = x;
    __syncthreads();
    if (w == 1) x += wsum[0];
    if (t < nchunk) part[rel * nchunk + t] = x - v;
    if (t == nchunk - 1) offs[(size_t)rel * (NB + 1) + NB] = x;
}

// phase 3: in-block exclusive scan + chunk offset. grid = 4*nchunk, block = 256.
__global__ void scan_write_kernel(const int* __restrict__ bins, const int* __restrict__ part,
                                  int* __restrict__ offs, int NB, int nchunk) {
    const int rel = blockIdx.x / nchunk;
    const int ch  = blockIdx.x % nchunk;
    const int t = threadIdx.x;
    const int lane = t & 63, w = t >> 6;
    const int base = ch * SCHUNK;
    const int* b = bins + (size_t)rel * NB + base;
    int* o = offs + (size_t)rel * (NB + 1) + base;
    const int lim = (NB - base < SCHUNK) ? (NB - base) : SCHUNK;
    const int i0 = t * 4;
    int v[4];
#pragma unroll
    for (int k = 0; k < 4; k++) v[k] = (i0 + k < lim) ? b[i0 + k] : 0;
    const int tsum = v[0] + v[1] + v[2] + v[3];
    int x = tsum;
#pragma unroll
    for (int d = 1; d < 64; d <<= 1) {
        int y = __shfl_up(x, (unsigned)d, 64);
        if (lane >= d) x += y;
    }
    __shared__ int wsum[4];
    if (lane == 63) wsum[w] = x;
    __syncthreads();
    int woff = 0;
#pragma unroll
    for (int k = 0; k < 4; k++) if (k < w) woff += wsum[k];
    int excl = woff + x - tsum + part[rel * nchunk + ch];
#pragma unroll
    for (int k = 0; k < 4; k++) {
        if (i0 + k < lim) { o[i0 + k] = excl; excl += v[k]; }
    }
}

struct RankArgs {
    const int* send[4];
    const int* recv[4];
    int*  perm[4];
    int2* pair[4];
    int E[4];
    const int* offs;   // 4*(NCELLS+1)
    int*       cur;    // 4*NCELLS
};

__global__ void rank4p_kernel(RankArgs a) {
    int i = blockIdx.x * blockDim.x + threadIdx.x;
    int rel = 0, j = i;
    while (rel < 4 && j >= a.E[rel]) { j -= a.E[rel]; rel++; }
    if (rel >= 4) return;
    int v = a.recv[rel][j];
    int p = a.offs[(size_t)rel * (NCELLS + 1) + v] +
            atomicAdd(&a.cur[(size_t)rel * NCELLS + v], 1);
    a.perm[rel][p] = j;
    a.pair[rel][p] = make_int2(a.send[rel][j], v);
}

// ---------------------------------------------------------------------------
// P-GEMM pair.
// ---------------------------------------------------------------------------
template <bool SAME>
__global__ __launch_bounds__(256, 4)
void pgemm2_kernel(const float* __restrict__ fA, const float* __restrict__ fB,
                   const unsigned short* __restrict__ W1T, const float* __restrict__ b1,
                   unsigned short* __restrict__ PA, unsigned short* __restrict__ PB,
                   int nblk)
{
    constexpr int AS = 136;
    __shared__ unsigned short A[64 * AS];

    const bool second = !SAME && ((int)blockIdx.x >= nblk);
    const float* f = second ? fB : fA;
    const int n0 = (second ? (int)blockIdx.x - nblk : (int)blockIdx.x) * 64;

    const int t = threadIdx.x;
    {
        const int rl = t >> 2, q = t & 3;
        int n = n0 + rl; n = (n < NCELLS) ? n : (NCELLS - 1);
        const float4* sp = (const float4*)(f + (size_t)n * CDIM + q * 32);
        unsigned short* arow = A + rl * AS + q * 32;
#pragma unroll
        for (int i = 0; i < 4; i++) {
            float4 a = sp[2 * i], b = sp[2 * i + 1];
            uint4 o;
            o.x = pkbf(a.x, a.y); o.y = pkbf(a.z, a.w);
            o.z = pkbf(b.x, b.y); o.w = pkbf(b.z, b.w);
            *(uint4*)(arow + i * 8) = o;
        }
    }
    __syncthreads();

    const int l = t & 63, w = t >> 6;
    const int lr = l & 15, lg = l >> 4;
    const int wr = (w & 1) * 32, wc = (w >> 1) * 64;

    const int nhalf = SAME ? 2 : 1;
#pragma unroll
    for (int h = 0; h < nhalf; h++) {
        const bool hiHalf = SAME ? (h == 1) : second;
        const int koff = hiHalf ? 4 : 0;
        unsigned short* P = hiHalf ? PB : PA;

        f32x4 acc[2][4];
#pragma unroll
        for (int mt = 0; mt < 2; mt++)
#pragma unroll
            for (int ct = 0; ct < 4; ct++) acc[mt][ct] = (f32x4){0.f, 0.f, 0.f, 0.f};

#pragma unroll
        for (int kt = 0; kt < 4; ++kt) {
            short8 av[2];
#pragma unroll
            for (int mt = 0; mt < 2; mt++)
                av[mt] = *(const short8*)(A + (wr + mt * 16 + lr) * AS + kt * 32 + lg * 8);
#pragma unroll
            for (int ct = 0; ct < 4; ct++) {
                const int cg = (wc >> 4) + ct;
                short8 bv = *(const short8*)(W1T + ((size_t)(cg * 9 + kt + koff) * 64 + l) * 8);
                acc[0][ct] = __builtin_amdgcn_mfma_f32_16x16x32_bf16(av[0], bv, acc[0][ct], 0, 0, 0);
                acc[1][ct] = __builtin_amdgcn_mfma_f32_16x16x32_bf16(av[1], bv, acc[1][ct], 0, 0, 0);
            }
        }

        float b1c[4];
#pragma unroll
        for (int ct = 0; ct < 4; ct++) b1c[ct] = hiHalf ? b1[wc + ct * 16 + lr] : 0.f;

#pragma unroll
        for (int mt = 0; mt < 2; mt++)
#pragma unroll
            for (int j = 0; j < 4; j++) {
                const int row = wr + mt * 16 + lg * 4 + j;
                const int n2  = n0 + row;
                if (n2 < NCELLS) {
#pragma unroll
                    for (int ct = 0; ct < 4; ct++)
                        P[(size_t)n2 * CDIM + wc + ct * 16 + lr] = cvt1bf(acc[mt][ct][j] + b1c[ct]);
                }
            }
    }
}

// ---------------------------------------------------------------------------
// EConv (r14 version, best measured): barrier-free; wave w owns edges
// 16w..16w+15 end-to-end; Ainv + cellid staged in LDS; one vmcnt(0) drain.
// Natural block order (r18 XCD swizzle measured -28%: Ps gather is the
// random-traffic source and is not localizable by block mapping).
// ---------------------------------------------------------------------------
template <int NINV>
__global__ __launch_bounds__(256, 4)
void econv_kernel(const unsigned short* __restrict__ Ps, const unsigned short* __restrict__ Pt,
                  const int* __restrict__ perm, const int2* __restrict__ pair,
                  const float* __restrict__ inv,
                  const unsigned short* __restrict__ W1T,
                  const unsigned short* __restrict__ W2T, const float* __restrict__ b2,
                  const float* __restrict__ Wg, const float* __restrict__ bg,
                  unsigned short* __restrict__ acc, int E)
{
    __shared__ unsigned short PsL[64 * 128];   // also Y (in-place)
    __shared__ unsigned short PtL[64 * 128];   // also O
    __shared__ unsigned short Ainv[64 * 40];
    __shared__ int cellid[64];

    const int t = threadIdx.x, l = t & 63, w = t >> 6;
    const int e0 = blockIdx.x * 64;
    const int base = w * 16;
    const int lr = l & 15, lg = l >> 4;

    // ---- async stage (wave-local rows base..base+15) ----
    {
        const int slot = l & 15;
        const int rsub = l >> 4;
#pragma unroll
        for (int i = 0; i < 4; i++) {
            const int r = base + i * 4 + rsub;
            int p = e0 + r; p = (p < E) ? p : (E - 1);
            const int2 sr = pair[p];
            const int ss = slot ^ (r & 7);
            load_lds16(Ps + (size_t)sr.x * CDIM + ss * 8, PsL + (base + i * 4) * 128, l);
            load_lds16(Pt + (size_t)sr.y * CDIM + ss * 8, PtL + (base + i * 4) * 128, l);
        }
    }
    // ---- cellid + Ainv (uint4 per lane; lanes<16 of each wave convert inv) ----
    {
        const int r = base + lr;
        uint4 u = make_uint4(0u, 0u, 0u, 0u);
        if (lg == 0) {
            int p = e0 + r; p = (p < E) ? p : (E - 1);
            const int j = perm[p];
            cellid[r] = pair[p].y;
            const float* ip = inv + (size_t)j * NINV;
            float v[8];
#pragma unroll
            for (int k = 0; k < 8; k++) v[k] = (k < NINV) ? ip[k] : 0.f;
            u.x = pkbf(v[0], v[1]);
            u.y = pkbf(v[2], v[3]);
            u.z = pkbf(v[4], v[5]);
            u.w = pkbf(v[6], v[7]);
        }
        *(uint4*)(Ainv + r * 40 + lg * 8) = u;
    }
    // drain this wave's global_load_lds (no block barrier)
    asm volatile("s_waitcnt vmcnt(0)" ::: "memory");

    // ---- inv MFMA: rows base..base+15, cols 0..127 (8 frags) ----
    f32x4 a1[8];
#pragma unroll
    for (int cg = 0; cg < 8; cg++) a1[cg] = (f32x4){0.f, 0.f, 0.f, 0.f};
    {
        short8 av = *(const short8*)(Ainv + (base + lr) * 40 + lg * 8);
#pragma unroll
        for (int cg = 0; cg < 8; cg++) {
            short8 bv = *(const short8*)(W1T + ((size_t)(cg * 9 + 8) * 64 + l) * 8);
            a1[cg] = __builtin_amdgcn_mfma_f32_16x16x32_bf16(av, bv, a1[cg], 0, 0, 0);
        }
    }

    // ---- phase A: PtL += a1 (scalar RMW, wave-local) ----
#pragma unroll
    for (int cg = 0; cg < 8; cg++) {
        const int col = cg * 16 + lr;
#pragma unroll
        for (int j = 0; j < 4; j++) {
            const int row = base + lg * 4 + j;
            const int idx = row * 128 + (col ^ ((row & 7) << 3));
            PtL[idx] = cvt1bf(bf2f(PtL[idx]) + a1[cg][j]);
        }
    }

    // ---- phase B: y = silu(Ps + Pt') vectorized, in place (wave-local) ----
    {
        const int rl = base + (l >> 2), q = l & 3;
        unsigned short* psrow = PsL + rl * 128;
        const unsigned short* ptrow = PtL + rl * 128;
#pragma unroll
        for (int i = 0; i < 4; i++) {
            const int sl = ((q * 4 + i) ^ (rl & 7)) * 8;
            uint4 us = *(const uint4*)(psrow + sl);
            uint4 ut = *(const uint4*)(ptrow + sl);
            uint4 o;
            o.x = silu2(us.x, ut.x);
            o.y = silu2(us.y, ut.y);
            o.z = silu2(us.z, ut.z);
            o.w = silu2(us.w, ut.w);
            *(uint4*)(psrow + sl) = o;
        }
    }

    // ---- layer 2: rows base+lr, all 128 cols (8 frags) ----
    f32x4 a2[8];
#pragma unroll
    for (int cg = 0; cg < 8; cg++) a2[cg] = (f32x4){0.f, 0.f, 0.f, 0.f};
#pragma unroll
    for (int kt = 0; kt < 4; ++kt) {
        const int row = base + lr;
        const int sl  = (kt * 4 + lg) ^ (row & 7);
        short8 av = *(const short8*)(PsL + row * 128 + sl * 8);
#pragma unroll
        for (int cg = 0; cg < 8; cg++) {
            short8 bv = *(const short8*)(W2T + ((size_t)(cg * 4 + kt) * 64 + l) * 8);
            a2[cg] = __builtin_amdgcn_mfma_f32_16x16x32_bf16(av, bv, a2[cg], 0, 0, 0);
        }
    }

    // ---- silu + gate (wave-local shfl reduce over lr) ----
    float wg[8], b2c[8];
#pragma unroll
    for (int cg = 0; cg < 8; cg++) {
        const int col = cg * 16 + lr;
        wg[cg]  = Wg[col];
        b2c[cg] = b2[col];
    }
#pragma unroll
    for (int cg = 0; cg < 8; cg++)
#pragma unroll
        for (int j = 0; j < 4; j++)
            a2[cg][j] = siluf(a2[cg][j] + b2c[cg]);

    const float bgs = bg[0];
    float g4[4];
#pragma unroll
    for (int j = 0; j < 4; j++) {
        float p = 0.f;
#pragma unroll
        for (int cg = 0; cg < 8; cg++) p += a2[cg][j] * wg[cg];
        p += __shfl_xor(p, 1, 16);
        p += __shfl_xor(p, 2, 16);
        p += __shfl_xor(p, 4, 16);
        p += __shfl_xor(p, 8, 16);
        const int row = base + lg * 4 + j;
        g4[j] = (e0 + row < E) ? sigf(p + bgs) : 0.f;
    }

    // ---- O-stage into PtL (wave-local) ----
#pragma unroll
    for (int cg = 0; cg < 8; cg++) {
        const int col = cg * 16 + lr;
#pragma unroll
        for (int j = 0; j < 4; j++) {
            const int row = base + lg * 4 + j;
            PtL[row * 128 + (col ^ ((row & 7) << 3))] = cvt1bf(a2[cg][j] * g4[j]);
        }
    }

    // ---- wave-uniform strip-scan reduction (bf16 acc) ----
    {
        const int pidx = e0 + base - 1;
        const int nidx = e0 + base + 16;
        const int cprev = (pidx >= 0) ? pair[(pidx < E) ? pidx : (E - 1)].y : -1;
        const int cnext = (nidx < E) ? pair[nidx].y : -1;

        unsigned vv[16];
        int cid[16];
#pragma unroll
        for (int i = 0; i < 16; i++) {
            const int r = base + i;
            const unsigned* prow = (const unsigned*)(PtL + r * 128);
            vv[i]  = prow[l ^ ((r & 7) << 2)];
            cid[i] = cellid[r];
        }

        unsigned* acc32 = (unsigned*)acc;
        float accL = 0.f, accH = 0.f;
        bool openLeft = (cid[0] == cprev);
#pragma unroll
        for (int i = 0; i < 16; i++) {
            if (i > 0 && cid[i] != cid[i - 1]) {
                const size_t di = (size_t)cid[i - 1] * 64 + l;
                if (openLeft) atomic_pk_bf16(acc32 + di, pkbf(accL, accH));
                else          acc32[di] = pkbf(accL, accH);
                accL = 0.f; accH = 0.f; openLeft = false;
            }
            accL += lo16(vv[i]);
            accH += hi16(vv[i]);
        }
        const bool openRight = (cid[15] == cnext);
        const size_t di = (size_t)cid[15] * 64 + l;
        if (openLeft || openRight) atomic_pk_bf16(acc32 + di, pkbf(accL, accH));
        else                       acc32[di] = pkbf(accL, accH);
    }
}

// ---------------------------------------------------------------------------
// Update MLP: out = f + silu([f | silu(acc1) | silu(acc2)] @ W1 + b1) @ W2 + b2
// ---------------------------------------------------------------------------
template <int F>
__global__ __launch_bounds__(256, F == 3 ? 3 : 4)
void update_kernel(const float* __restrict__ f,
                   const unsigned short* __restrict__ s1, const unsigned short* __restrict__ s2,
                   const unsigned short* __restrict__ W1T, const float* __restrict__ b1,
                   const unsigned short* __restrict__ W2T, const float* __restrict__ b2,
                   float* __restrict__ out)
{
    constexpr int K   = F * CDIM;
    constexpr int KT1 = K / 32;
    constexpr int AS  = K + 8;
    constexpr int YS  = 136;
    __shared__ unsigned short U[64 * AS];   // union: A | Y
    unsigned short* Alds = U;
    unsigned short* Ylds = U;

    const int t  = threadIdx.x;
    const int n0 = blockIdx.x * 64;
    const int w = t >> 6, l = t & 63;

    // ---- phase 1: build A-tile [f | silu(s1) | silu(s2)] ----
    {
        const int rl = t >> 2, q = t & 3;
        int n = n0 + rl; n = (n < NCELLS) ? n : (NCELLS - 1);
        unsigned short* arow = Alds + rl * AS;
        {
            const float4* sp = (const float4*)(f + (size_t)n * CDIM + q * 32);
#pragma unroll
            for (int i = 0; i < 4; i++) {
                float4 a = sp[2 * i], b = sp[2 * i + 1];
                uint4 o;
                o.x = pkbf(a.x, a.y); o.y = pkbf(a.z, a.w);
                o.z = pkbf(b.x, b.y); o.w = pkbf(b.z, b.w);
                *(uint4*)(arow + q * 32 + i * 8) = o;
            }
        }
#pragma unroll
        for (int p = 1; p < F; p++) {
            const unsigned short* accp = (p == 1) ? s1 : s2;
            const uint4* sp = (const uint4*)(accp + (size_t)n * CDIM + q * 32);
            uint4* dstv = (uint4*)(arow + p * CDIM + q * 32);
#pragma unroll
            for (int i = 0; i < 4; i++) {
                uint4 v = sp[i];
                uint4 o;
                o.x = silu1(v.x); o.y = silu1(v.y);
                o.z = silu1(v.z); o.w = silu1(v.w);
                dstv[i] = o;
            }
        }
    }
    __syncthreads();

    const int lr = l & 15, lg = l >> 4;
    const int wr = (w & 1) * 32;
    const int wc = (w >> 1) * 64;

    f32x4 a1[2][4];
#pragma unroll
    for (int mt = 0; mt < 2; mt++)
#pragma unroll
        for (int ct = 0; ct < 4; ct++) a1[mt][ct] = (f32x4){0.f, 0.f, 0.f, 0.f};

    for (int kt = 0; kt < KT1; ++kt) {
        short8 av[2];
#pragma unroll
        for (int mt = 0; mt < 2; mt++)
            av[mt] = *(const short8*)(Alds + (wr + mt * 16 + lr) * AS + kt * 32 + lg * 8);
#pragma unroll
        for (int ct = 0; ct < 4; ct++) {
            const int cg = (wc >> 4) + ct;
            short8 bv = *(const short8*)(W1T + ((size_t)(cg * KT1 + kt) * 64 + l) * 8);
            a1[0][ct] = __builtin_amdgcn_mfma_f32_16x16x32_bf16(av[0], bv, a1[0][ct], 0, 0, 0);
            a1[1][ct] = __builtin_amdgcn_mfma_f32_16x16x32_bf16(av[1], bv, a1[1][ct], 0, 0, 0);
        }
    }
    __syncthreads();   // A consumed; Y overwrites

#pragma unroll
    for (int ct = 0; ct < 4; ct++) {
        const int col = wc + ct * 16 + lr;
        const float bb = b1[col];
#pragma unroll
        for (int mt = 0; mt < 2; mt++)
#pragma unroll
            for (int j = 0; j < 4; j++) {
                const int row = wr + mt * 16 + lg * 4 + j;
                Ylds[row * YS + col] = cvt1bf(siluf(a1[mt][ct][j] + bb));
            }
    }
    __syncthreads();

    f32x4 a2[2][4];
#pragma unroll
    for (int mt = 0; mt < 2; mt++)
#pragma unroll
        for (int ct = 0; ct < 4; ct++) a2[mt][ct] = (f32x4){0.f, 0.f, 0.f, 0.f};

    for (int kt = 0; kt < 4; ++kt) {
        short8 av[2];
#pragma unroll
        for (int mt = 0; mt < 2; mt++)
            av[mt] = *(const short8*)(Ylds + (wr + mt * 16 + lr) * YS + kt * 32 + lg * 8);
#pragma unroll
        for (int ct = 0; ct < 4; ct++) {
            const int cg = (wc >> 4) + ct;
            short8 bv = *(const short8*)(W2T + ((size_t)(cg * 4 + kt) * 64 + l) * 8);
            a2[0][ct] = __builtin_amdgcn_mfma_f32_16x16x32_bf16(av[0], bv, a2[0][ct], 0, 0, 0);
            a2[1][ct] = __builtin_amdgcn_mfma_f32_16x16x32_bf16(av[1], bv, a2[1][ct], 0, 0, 0);
        }
    }

    float b2c[4];
#pragma unroll
    for (int ct = 0; ct < 4; ct++) b2c[ct] = b2[wc + ct * 16 + lr];

#pragma unroll
    for (int mt = 0; mt < 2; mt++)
#pragma unroll
        for (int j = 0; j < 4; j++) {
            const int row = wr + mt * 16 + lg * 4 + j;
            const int n2  = n0 + row;
            if (n2 < NCELLS) {
#pragma unroll
                for (int ct = 0; ct < 4; ct++) {
                    const int col = wc + ct * 16 + lr;
                    out[(size_t)n2 * CDIM + col] =
                        f[(size_t)n2 * CDIM + col] + a2[mt][ct][j] + b2c[ct];
                }
            }
        }
}

// ---------------------------------------------------------------------------
extern "C" void kernel_launch(void* const* d_in, const int* in_sizes, int n_in,
                              void* d_out, int out_size, void* d_ws, size_t ws_size,
                              hipStream_t stream)
{
    const float* f0 = (const float*)d_in[0];
    const float* f1 = (const float*)d_in[1];
    const float* f2 = (const float*)d_in[2];

    const int*   a0_send = (const int*)d_in[3];
    const int*   a0_recv = (const int*)d_in[4];
    const float* inv_a0  = (const float*)d_in[5];
    const float* a0_b1   = (const float*)d_in[7];
    const float* a0_b2   = (const float*)d_in[9];
    const float* a0_Wg   = (const float*)d_in[10];
    const float* a0_bg   = (const float*)d_in[11];

    const int*   a1_send = (const int*)d_in[12];
    const int*   a1_recv = (const int*)d_in[13];
    const float* inv_a1  = (const float*)d_in[14];
    const float* a1_b1   = (const float*)d_in[16];
    const float* a1_b2   = (const float*)d_in[18];
    const float* a1_Wg   = (const float*)d_in[19];
    const float* a1_bg   = (const float*)d_in[20];

    const int*   i1_send = (const int*)d_in[21];
    const int*   i1_recv = (const int*)d_in[22];
    const float* inv_i1  = (const float*)d_in[23];
    const float* i1_b1   = (const float*)d_in[25];
    const float* i1_b2   = (const float*)d_in[27];
    const float* i1_Wg   = (const float*)d_in[28];
    const float* i1_bg   = (const float*)d_in[29];

    const int*   i2_send = (const int*)d_in[30];
    const int*   i2_recv = (const int*)d_in[31];
    const float* inv_i2  = (const float*)d_in[32];
    const float* i2_b1   = (const float*)d_in[34];
    const float* i2_b2   = (const float*)d_in[36];
    const float* i2_Wg   = (const float*)d_in[37];
    const float* i2_bg   = (const float*)d_in[38];

    const float* u0_b1 = (const float*)d_in[40];
    const float* u0_b2 = (const float*)d_in[42];
    const float* u1_b1 = (const float*)d_in[44];
    const float* u1_b2 = (const float*)d_in[46];
    const float* u2_b1 = (const float*)d_in[48];
    const float* u2_b2 = (const float*)d_in[50];

    const int E_a0 = in_sizes[3];
    const int E_a1 = in_sizes[12];
    const int E_i1 = in_sizes[21];
    const int E_i2 = in_sizes[30];
    const int Es[4] = {E_a0, E_a1, E_i1, E_i2};

    // ---- ws bump allocator ----
    char* base = (char*)d_ws;
    size_t off = 0;
    auto alloc = [&](size_t bytes) -> char* {
        off = (off + 255) & ~(size_t)255;
        char* p = base + off;
        off += bytes;
        return p;
    };
    unsigned short* wb  = (unsigned short*)alloc(753664);
    int* offs_all = (int*)alloc((size_t)4 * (NCELLS + 1) * sizeof(int));
    int* bins_all = (int*)alloc((size_t)4 * NCELLS * sizeof(int));   // also cursor
    const int nchunk = (NCELLS + SCHUNK - 1) / SCHUNK;
    int* part = (int*)alloc((size_t)4 * nchunk * sizeof(int));
    int* perm[4];
    int2* pair[4];
    for (int r = 0; r < 4; r++) {
        perm[r] = (int*)alloc((size_t)Es[r] * sizeof(int));
        pair[r] = (int2*)alloc((size_t)Es[r] * sizeof(int2));
    }
    unsigned short* accA = (unsigned short*)alloc((size_t)NCELLS * CDIM * sizeof(unsigned short));
    unsigned short* accB = (unsigned short*)alloc((size_t)NCELLS * CDIM * sizeof(unsigned short));
    unsigned short* PsT = (unsigned short*)alloc((size_t)NCELLS * CDIM * sizeof(unsigned short));
    unsigned short* PtT = (unsigned short*)alloc((size_t)NCELLS * CDIM * sizeof(unsigned short));

    // ---- weight prep ----
    const int o_w1[4]  = {0, 36864, 73728, 110592};
    const int o_w2[4]  = {147456, 163840, 180224, 196608};
    const int o_uw1[3] = {212992, 245760, 294912};
    const int o_uw2[3] = {327680, 344064, 360448};

    PrepArgs pa;
    int idx = 0, cum = 0;
    auto add = [&](const void* s, int fin, int ktc, int woff) {
        pa.src[idx] = (const float*)s; pa.fin[idx] = fin; pa.ktc[idx] = ktc;
        pa.dstoff[idx] = woff; cum += ktc * 8; pa.tend[idx] = cum; idx++;
    };
    add(d_in[6],  259, 9,  o_w1[0]);
    add(d_in[15], 262, 9,  o_w1[1]);
    add(d_in[24], 259, 9,  o_w1[2]);
    add(d_in[33], 262, 9,  o_w1[3]);
    add(d_in[8],  128, 4,  o_w2[0]);
    add(d_in[17], 128, 4,  o_w2[1]);
    add(d_in[26], 128, 4,  o_w2[2]);
    add(d_in[35], 128, 4,  o_w2[3]);
    add(d_in[39], 256, 8,  o_uw1[0]);
    add(d_in[43], 384, 12, o_uw1[1]);
    add(d_in[47], 256, 8,  o_uw1[2]);
    add(d_in[41], 128, 4,  o_uw2[0]);
    add(d_in[45], 128, 4,  o_uw2[1]);
    add(d_in[49], 128, 4,  o_uw2[2]);
    prep_kernel<<<cum, 64, 0, stream>>>(pa, wb);

    // ---- CSR build: hist -> 3-phase scan -> rank ----
    const int Etot = E_a0 + E_a1 + E_i1 + E_i2;
    hipMemsetAsync(bins_all, 0, (size_t)4 * NCELLS * sizeof(int), stream);
    hist4_kernel<<<(Etot + 255) / 256, 256, 0, stream>>>(
        a0_recv, a1_recv, i1_recv, i2_recv, E_a0, E_a1, E_i1, E_i2, bins_all);
    scan_sum_kernel<<<4 * nchunk, 256, 0, stream>>>(bins_all, part, NCELLS, nchunk);
    scan_part_kernel<<<4, 128, 0, stream>>>(part, offs_all, NCELLS, nchunk);
    scan_write_kernel<<<4 * nchunk, 256, 0, stream>>>(bins_all, part, offs_all, NCELLS, nchunk);
    hipMemsetAsync(bins_all, 0, (size_t)4 * NCELLS * sizeof(int), stream);
    {
        RankArgs ra;
        const int* sends[4] = {a0_send, a1_send, i1_send, i2_send};
        const int* recvs[4] = {a0_recv, a1_recv, i1_recv, i2_recv};
        for (int r = 0; r < 4; r++) {
            ra.send[r] = sends[r]; ra.recv[r] = recvs[r];
            ra.perm[r] = perm[r]; ra.pair[r] = pair[r]; ra.E[r] = Es[r];
        }
        ra.offs = offs_all; ra.cur = bins_all;
        rank4p_kernel<<<(Etot + 255) / 256, 256, 0, stream>>>(ra);
    }

    const size_t accBytes = (size_t)NCELLS * CDIM * sizeof(unsigned short);
    hipMemsetAsync(accA, 0, accBytes, stream);
    hipMemsetAsync(accB, 0, accBytes, stream);

    float* out = (float*)d_out;
    const int UPD_BLK = (NCELLS + 63) / 64;
    const int PG_BLK  = UPD_BLK;

    // rank 0: a0 -> accA
    pgemm2_kernel<true><<<PG_BLK, 256, 0, stream>>>(
        f0, f0, wb + o_w1[0], a0_b1, PsT, PtT, PG_BLK);
    econv_kernel<3><<<(E_a0 + 63) / 64, 256, 0, stream>>>(
        PsT, PtT, perm[0], pair[0], inv_a0,
        wb + o_w1[0], wb + o_w2[0], a0_b2, a0_Wg, a0_bg, accA, E_a0);
    update_kernel<2><<<UPD_BLK, 256, 0, stream>>>(
        f0, accA, nullptr, wb + o_uw1[0], u0_b1, wb + o_uw2[0], u0_b2, out);
    hipMemsetAsync(accA, 0, accBytes, stream);

    // rank 1: a1 -> accA, i1 -> accB
    pgemm2_kernel<true><<<PG_BLK, 256, 0, stream>>>(
        f1, f1, wb + o_w1[1], a1_b1, PsT, PtT, PG_BLK);
    econv_kernel<6><<<(E_a1 + 63) / 64, 256, 0, stream>>>(
        PsT, PtT, perm[1], pair[1], inv_a1,
        wb + o_w1[1], wb + o_w2[1], a1_b2, a1_Wg, a1_bg, accA, E_a1);
    pgemm2_kernel<false><<<2 * PG_BLK, 256, 0, stream>>>(
        f0, f1, wb + o_w1[2], i1_b1, PsT, PtT, PG_BLK);
    econv_kernel<3><<<(E_i1 + 63) / 64, 256, 0, stream>>>(
        PsT, PtT, perm[2], pair[2], inv_i1,
        wb + o_w1[2], wb + o_w2[2], i1_b2, i1_Wg, i1_bg, accB, E_i1);
    update_kernel<3><<<UPD_BLK, 256, 0, stream>>>(
        f1, accA, accB, wb + o_uw1[1], u1_b1, wb + o_uw2[1], u1_b2,
        out + (size_t)NCELLS * CDIM);
    hipMemsetAsync(accA, 0, accBytes, stream);

    // rank 2: i2 -> accA
    pgemm2_kernel<false><<<2 * PG_BLK, 256, 0, stream>>>(
        f1, f2, wb + o_w1[3], i2_b1, PsT, PtT, PG_BLK);
    econv_kernel<6><<<(E_i2 + 63) / 64, 256, 0, stream>>>(
        PsT, PtT, perm[3], pair[3], inv_i2,
        wb + o_w1[3], wb + o_w2[3], i2_b2, i2_Wg, i2_bg, accA, E_i2);
    update_kernel<2><<<UPD_BLK, 256, 0, stream>>>(
        f2, accA, nullptr, wb + o_uw1[2], u2_b1, wb + o_uw2[2], u2_b2,
        out + 2 * (size_t)NCELLS * CDIM);
}